// Round 1
// baseline (1722.640 us; speedup 1.0000x reference)
//
#include <hip/hip_runtime.h>
#include <hip/hip_fp16.h>

// RNN_16492674416646: h_t = tanh(x_t W_ih^T + b_ih + b_hh + h_{t-1} W_hh^T),
// out_t = h_t W_out^T + b_out. T=2048, B=128, IN=2, H=200, OUT=1, fp32.
//
// R14 = R13 with exec-masked A-fragment loads.
// R13 counters: MfmaUtil 14%, VALUBusy 22%, 0 bank conflicts, 1305 cyc/step.
// Theory: A-loads (13 waves x 7 ds_read_b128 = 93 KB/step through the LDS
// return path, ~730 cyc at 128 B/cyc) dominate the step, even though only
// A rows 0 (h_hi) and 1 (h_lo) are consumed -- D rows 2..15 are dead.
// Fix: load A only on lanes with (lane&15) < 2 (8/64 lanes -> 128 B unique
// per read, zero redundancy); dead rows hold a one-time zero. MFMA rows are
// independent, rows >=2 of D are never read, so this is bit-identical for
// the live rows. LDS return traffic: 93 KB -> 11.6 KB per step.
//
// Everything else identical to R13: 16 waves (4/SIMD), 13 tile-waves,
// fp16 W + split-fp16 h (hi on row 0, lo on row 1), 4+3 MFMA chain split,
// bank-disjoint 9-slot ring, drain every 9 steps by waves 0..8.
// Precision unchanged: R13 absmax 0.0078 < 0.029 thr.

typedef short s8v __attribute__((ext_vector_type(8)));   // 8 x fp16 bits
typedef float f4v __attribute__((ext_vector_type(4)));

static constexpr int T = 2048;
static constexpr int B = 128;
static constexpr int H = 200;
static constexpr int NTHR = 1024;  // 16 waves
static constexpr int NT  = 13;     // n-tiles of 16 (208 >= 200)
static constexpr int KT  = 7;      // k-tiles of 32 (224 padded)
static constexpr int HP  = 224;    // padded H
static constexpr int RS  = 9;      // ring slots

__device__ __forceinline__ unsigned short f2h(float f) {
    const __half h = __float2half_rn(f);
    return *(const unsigned short*)&h;
}
__device__ __forceinline__ float h2f(unsigned short u) {
    const __half h = *(const __half*)&u;
    return __half2float(h);
}

__global__ __attribute__((amdgpu_flat_work_group_size(NTHR, NTHR),
                          amdgpu_waves_per_eu(4, 4)))
void rnn_fused(const float* __restrict__ x,     // [T,B,2]
               const float* __restrict__ W_ih,  // [H,2]
               const float* __restrict__ W_hh,  // [H,H]
               const float* __restrict__ b_ih,  // [H]
               const float* __restrict__ b_hh,  // [H]
               const float* __restrict__ W_out, // [1,H]
               const float* __restrict__ b_out, // [1]
               float* __restrict__ out)         // [T,B]
{
    const int b    = blockIdx.x;
    const int tid  = threadIdx.x;
    const int w    = tid >> 6;       // wave id 0..15
    const int lane = tid & 63;
    const int m    = lane & 15;      // A-row sel / B-col / D-col
    const int q    = lane >> 4;      // k-quad

    const bool hasT = (w < NT);      // waves 13..15: barrier/drain only
    const int  nA   = 16 * w + m;    // this wave's output col (if hasT)
    const bool colv = hasT && (nA < H);

    // ring[slot][hi=0/lo=1][col]; lo offset 448 B = 64 mod 128 (see header)
    __shared__ __align__(16) unsigned short ring[RS][2][HP];
    __shared__ float xs[2 * T];      // x column (16 KB)

    for (int i = tid; i < RS * 2 * HP; i += NTHR) (&ring[0][0][0])[i] = 0;
    for (int idx = tid; idx < T; idx += NTHR) {
        const float2 v = *(const float2*)(x + (size_t)idx * (B * 2) + 2 * b);
        xs[2 * idx] = v.x; xs[2 * idx + 1] = v.y;
    }

    // --- loop-invariant B-fragment (fp16): B[k][n]=W_hh[n][k], n=nA ---
    s8v BA[KT];
#pragma unroll
    for (int kt = 0; kt < KT; ++kt) {
        s8v ba{};
        if (colv) {
#pragma unroll
            for (int j = 0; j < 8; ++j) {
                const int ks = 32 * kt + 8 * q + j;
                ba[j] = (short)((ks < H) ? f2h(W_hh[nA * H + ks])
                                         : (unsigned short)0);
            }
        }
        BA[kt] = ba;
    }

    // --- epilogue constants (q==0 lanes of tile waves own col nA) ---
    const float wxA0 = colv ? W_ih[nA * 2]     : 0.f;
    const float wxA1 = colv ? W_ih[nA * 2 + 1] : 0.f;
    const float bA   = colv ? (b_ih[nA] + b_hh[nA]) : 0.f;

    // --- head constants ---
    const float wo0 = W_out[lane];
    const float wo1 = W_out[64 + lane];
    const float wo2 = W_out[128 + lane];
    const float wo3 = (192 + lane < H) ? W_out[192 + lane] : 0.f;
    const float bo  = b_out[0];

    __syncthreads();

    float* op = out + b;

    auto drain = [&](int slot, int tout) {
        float v = (h2f(ring[slot][0][lane])     + h2f(ring[slot][1][lane]))     * wo0
                + (h2f(ring[slot][0][64+lane])  + h2f(ring[slot][1][64+lane]))  * wo1
                + (h2f(ring[slot][0][128+lane]) + h2f(ring[slot][1][128+lane])) * wo2;
        if (lane < 32)   // cols 192..223: pads stay 0, wo3 = 0 past 199
            v += (h2f(ring[slot][0][192+lane]) + h2f(ring[slot][1][192+lane])) * wo3;
#pragma unroll
        for (int off = 32; off > 0; off >>= 1)
            v += __shfl_down(v, off, 64);
        if (lane == 0) op[(size_t)tout * B] = v + bo;
    };

    // A fragments live across the whole t-loop. Lanes with m >= 2 feed dead
    // MFMA rows (2..15); they hold 0 forever (zero-init below). Only the 8
    // lanes with m < 2 (rows 0=h_hi, 1=h_lo) re-load each step.
    s8v A[KT];
#pragma unroll
    for (int kt = 0; kt < KT; ++kt) A[kt] = s8v{};

    int rp = 0;                          // t % 9
    for (int t = 0; t < T; ++t) {
        // --- drain every 9 steps: slot s holds h of step t-9+s, all stable
        // since their own steps' end barriers; extra barrier orders the
        // subsequent rewrite of slot 0. ---
        if (rp == 0 && t) {
            if (w < RS) drain(w, t - RS + w);   // waves 0..8 -> slots 0..8
            __syncthreads();
        }
        const int sr = rp ? rp - 1 : RS - 1;
        const int sw = rp;
        const float x0 = xs[2 * t], x1 = xs[2 * t + 1];

        if (hasT) {
            // masked A-load: 8/64 lanes (rows 0,1 = h_hi,h_lo), 128 B unique
            // per ds_read_b128 instead of 1024 B of 16-lane broadcast dup.
            if (m < 2) {
                const unsigned short* lp = &ring[sr][m][8 * q];
#pragma unroll
                for (int kt = 0; kt < KT; ++kt)
                    A[kt] = *(const s8v*)(lp + 32 * kt);
            }

            // two independent 4/3-deep chains -> ~half the dep latency
            f4v u = {0.f, 0.f, 0.f, 0.f};
            f4v v = {0.f, 0.f, 0.f, 0.f};
            u = __builtin_amdgcn_mfma_f32_16x16x32_f16(A[0], BA[0], u, 0, 0, 0);
            v = __builtin_amdgcn_mfma_f32_16x16x32_f16(A[4], BA[4], v, 0, 0, 0);
            u = __builtin_amdgcn_mfma_f32_16x16x32_f16(A[1], BA[1], u, 0, 0, 0);
            v = __builtin_amdgcn_mfma_f32_16x16x32_f16(A[5], BA[5], v, 0, 0, 0);
            u = __builtin_amdgcn_mfma_f32_16x16x32_f16(A[2], BA[2], u, 0, 0, 0);
            v = __builtin_amdgcn_mfma_f32_16x16x32_f16(A[6], BA[6], v, 0, 0, 0);
            u = __builtin_amdgcn_mfma_f32_16x16x32_f16(A[3], BA[3], u, 0, 0, 0);

            // epilogue: q==0 lanes hold D rows 0 (W.h_hi) and 1 (W.h_lo)
            if (q == 0 && nA < H) {
                const float y   = (u[0] + u[1]) + (v[0] + v[1]);
                const float pre = y + fmaf(x0, wxA0, fmaf(x1, wxA1, bA));
                const float e   = __expf(2.f * pre);      // tanh, saturating
                const float th  = 1.f - 2.f / (e + 1.f);
                const unsigned short hi = f2h(th);
                ring[sw][0][nA] = hi;
                ring[sw][1][nA] = f2h(th - h2f(hi));
            }
        }
        __syncthreads();
        if (++rp == RS) rp = 0;
    }

    // --- tail: T mod 9 = 5 steps (2043..2047) sit in slots 0..4 ---
    const int rem = T % RS;
    if (w < rem) drain(w, T - rem + w);
}

extern "C" void kernel_launch(void* const* d_in, const int* in_sizes, int n_in,
                              void* d_out, int out_size, void* d_ws, size_t ws_size,
                              hipStream_t stream) {
    const float* x     = (const float*)d_in[0];
    const float* W_ih  = (const float*)d_in[1];
    const float* W_hh  = (const float*)d_in[2];
    const float* b_ih  = (const float*)d_in[3];
    const float* b_hh  = (const float*)d_in[4];
    const float* W_out = (const float*)d_in[5];
    const float* b_out = (const float*)d_in[6];
    float* out = (float*)d_out;

    rnn_fused<<<B, NTHR, 0, stream>>>(x, W_ih, W_hh, b_ih, b_hh, W_out, b_out, out);
}

// Round 2
// 1291.529 us; speedup vs baseline: 1.3338x; 1.3338x over previous
//
#include <hip/hip_runtime.h>
#include <hip/hip_fp16.h>

// RNN_16492674416646: h_t = tanh(x_t W_ih^T + b_ih + b_hh + h_{t-1} W_hh^T),
// out_t = h_t W_out^T + b_out. T=2048, B=128, IN=2, H=200, OUT=1, fp32.
//
// R15: LDS-instruction-count cut. R13 was bound by ds_read_b128 ISSUE count:
// 13 tile-waves x 7 + writes ~= 112 reads/step x ~11 cyc ~= 1260 cyc ~=
// measured 1305 cyc/step (ds_read_b128 occupies the LDS pipe ~10-12 cyc per
// INSTRUCTION regardless of lane duplication -- R14's lane-masking proved
// this by not helping). All 13 waves read the IDENTICAL A fragment (h).
// Fix: 8 tile-waves (512 thr), 2 n-tiles/wave sharing ONE A-read set:
// 56 reads/step (~620 cyc). MFMA issue (worst SIMD: 4 tiles = 28 MFMA
// x ~20cyc ~= 577 cyc) becomes co-limiter. Tiles/wave {2,2,2,1,2,1,1,2}
// balances both (w, w+4) and (2w, 2w+1) wave->SIMD pairings at <=4 tiles.
// 2 waves/SIMD -> 256-VGPR budget; 2-tile wave ~125 regs, no churn
// (R12's churn was 14 B-frags under a 128-reg cap; cap is now 256).
// Ring RS=8 (T%8=0, no tail); slot stride 896 B == 0 mod 128 so the
// hi/lo bank-disjoint split (lo at +448 B = 64 mod 128) is preserved.
// Precision identical to R13 (same per-tile math): absmax 0.0078 < 0.029.

typedef short s8v __attribute__((ext_vector_type(8)));   // 8 x fp16 bits
typedef float f4v __attribute__((ext_vector_type(4)));

static constexpr int T = 2048;
static constexpr int B = 128;
static constexpr int H = 200;
static constexpr int NTHR = 512;   // 8 waves
static constexpr int KT  = 7;      // k-tiles of 32 (224 padded)
static constexpr int HP  = 224;    // padded H
static constexpr int RS  = 8;      // ring slots; T % RS == 0

__device__ __forceinline__ unsigned short f2h(float f) {
    const __half h = __float2half_rn(f);
    return *(const unsigned short*)&h;
}
__device__ __forceinline__ float h2f(unsigned short u) {
    const __half h = *(const __half*)&u;
    return __half2float(h);
}

__global__ __attribute__((amdgpu_flat_work_group_size(NTHR, NTHR),
                          amdgpu_waves_per_eu(2, 2)))
void rnn_fused(const float* __restrict__ x,     // [T,B,2]
               const float* __restrict__ W_ih,  // [H,2]
               const float* __restrict__ W_hh,  // [H,H]
               const float* __restrict__ b_ih,  // [H]
               const float* __restrict__ b_hh,  // [H]
               const float* __restrict__ W_out, // [1,H]
               const float* __restrict__ b_out, // [1]
               float* __restrict__ out)         // [T,B]
{
    const int b    = blockIdx.x;
    const int tid  = threadIdx.x;
    const int w    = tid >> 6;       // wave id 0..7
    const int lane = tid & 63;
    const int m    = lane & 15;      // A-row sel / B-col / D-col
    const int q    = lane >> 4;      // k-quad

    // tile assignment: counts {2,2,2,1,2,1,1,2}, contiguous starts
    // {0,2,4,6,7,9,10,11} -> balanced under (w,w+4) and (2w,2w+1) pairings.
    const int dfc = (w > 3) + (w > 5) + (w > 6);
    const int t0  = 2 * w - dfc;
    const int tn  = (w == 3 || w == 5 || w == 6) ? 1 : 2;
    const int nA0 = 16 * t0 + m;
    const int nA1 = 16 * (t0 + 1) + m;
    const bool cv0 = (nA0 < H);
    const bool cv1 = (tn > 1) && (nA1 < H);

    // ring[slot][hi=0/lo=1][col]; lo offset 448 B = 64 mod 128 -> per-kt
    // chunk hi hits banks 16kt..16kt+15, lo the complementary half.
    __shared__ __align__(16) unsigned short ring[RS][2][HP];
    __shared__ float xs[2 * T];      // x column (16 KB)

    for (int i = tid; i < RS * 2 * HP; i += NTHR) (&ring[0][0][0])[i] = 0;
    for (int idx = tid; idx < T; idx += NTHR) {
        const float2 v = *(const float2*)(x + (size_t)idx * (B * 2) + 2 * b);
        xs[2 * idx] = v.x; xs[2 * idx + 1] = v.y;
    }

    // --- loop-invariant B-fragments (fp16): B[k][n]=W_hh[n][k] ---
    s8v BA0[KT], BA1[KT];
#pragma unroll
    for (int kt = 0; kt < KT; ++kt) {
        s8v b0{}, b1{};
        if (cv0) {
#pragma unroll
            for (int j = 0; j < 8; ++j) {
                const int ks = 32 * kt + 8 * q + j;
                b0[j] = (short)((ks < H) ? f2h(W_hh[nA0 * H + ks])
                                         : (unsigned short)0);
            }
        }
        if (cv1) {
#pragma unroll
            for (int j = 0; j < 8; ++j) {
                const int ks = 32 * kt + 8 * q + j;
                b1[j] = (short)((ks < H) ? f2h(W_hh[nA1 * H + ks])
                                         : (unsigned short)0);
            }
        }
        BA0[kt] = b0; BA1[kt] = b1;
    }

    // --- epilogue constants (q==0 lanes own cols nA0 / nA1) ---
    const float wx00 = cv0 ? W_ih[nA0 * 2]     : 0.f;
    const float wx01 = cv0 ? W_ih[nA0 * 2 + 1] : 0.f;
    const float bA0  = cv0 ? (b_ih[nA0] + b_hh[nA0]) : 0.f;
    const float wx10 = cv1 ? W_ih[nA1 * 2]     : 0.f;
    const float wx11 = cv1 ? W_ih[nA1 * 2 + 1] : 0.f;
    const float bA1  = cv1 ? (b_ih[nA1] + b_hh[nA1]) : 0.f;

    // --- head constants ---
    const float wo0 = W_out[lane];
    const float wo1 = W_out[64 + lane];
    const float wo2 = W_out[128 + lane];
    const float wo3 = (192 + lane < H) ? W_out[192 + lane] : 0.f;
    const float bo  = b_out[0];

    __syncthreads();

    float* op = out + b;

    auto drain = [&](int slot, int tout) {
        float v = (h2f(ring[slot][0][lane])     + h2f(ring[slot][1][lane]))     * wo0
                + (h2f(ring[slot][0][64+lane])  + h2f(ring[slot][1][64+lane]))  * wo1
                + (h2f(ring[slot][0][128+lane]) + h2f(ring[slot][1][128+lane])) * wo2;
        if (lane < 32)   // cols 192..223: pads stay 0, wo3 = 0 past 199
            v += (h2f(ring[slot][0][192+lane]) + h2f(ring[slot][1][192+lane])) * wo3;
#pragma unroll
        for (int off = 32; off > 0; off >>= 1)
            v += __shfl_down(v, off, 64);
        if (lane == 0) op[(size_t)tout * B] = v + bo;
    };

    int rp = 0;                          // t % RS
    for (int t = 0; t < T; ++t) {
        // --- drain every RS steps: slot s holds h of step t-RS+s, all
        // stable since their steps' end barriers; extra barrier orders the
        // subsequent rewrite of slot 0. All 8 waves drain one slot each. ---
        if (rp == 0 && t) {
            drain(w, t - RS + w);
            __syncthreads();
        }
        const int sr = rp ? rp - 1 : RS - 1;
        const int sw = rp;
        const float x0 = xs[2 * t], x1 = xs[2 * t + 1];

        // A: row 0 <- h_hi, row 1 <- h_lo, rows 2..15 dup hi (ignored).
        // ONE read set shared by both of this wave's n-tiles.
        const unsigned short* lp = &ring[sr][(m == 1) ? 1 : 0][8 * q];
        s8v A[KT];
#pragma unroll
        for (int kt = 0; kt < KT; ++kt) A[kt] = *(const s8v*)(lp + 32 * kt);

        if (tn == 2) {
            // 4 independent chains (2 tiles x 4/3 split) -> depth <= 4
            f4v u0 = {0.f, 0.f, 0.f, 0.f};
            f4v v0 = {0.f, 0.f, 0.f, 0.f};
            f4v u1 = {0.f, 0.f, 0.f, 0.f};
            f4v v1 = {0.f, 0.f, 0.f, 0.f};
            u0 = __builtin_amdgcn_mfma_f32_16x16x32_f16(A[0], BA0[0], u0, 0, 0, 0);
            u1 = __builtin_amdgcn_mfma_f32_16x16x32_f16(A[0], BA1[0], u1, 0, 0, 0);
            v0 = __builtin_amdgcn_mfma_f32_16x16x32_f16(A[4], BA0[4], v0, 0, 0, 0);
            v1 = __builtin_amdgcn_mfma_f32_16x16x32_f16(A[4], BA1[4], v1, 0, 0, 0);
            u0 = __builtin_amdgcn_mfma_f32_16x16x32_f16(A[1], BA0[1], u0, 0, 0, 0);
            u1 = __builtin_amdgcn_mfma_f32_16x16x32_f16(A[1], BA1[1], u1, 0, 0, 0);
            v0 = __builtin_amdgcn_mfma_f32_16x16x32_f16(A[5], BA0[5], v0, 0, 0, 0);
            v1 = __builtin_amdgcn_mfma_f32_16x16x32_f16(A[5], BA1[5], v1, 0, 0, 0);
            u0 = __builtin_amdgcn_mfma_f32_16x16x32_f16(A[2], BA0[2], u0, 0, 0, 0);
            u1 = __builtin_amdgcn_mfma_f32_16x16x32_f16(A[2], BA1[2], u1, 0, 0, 0);
            v0 = __builtin_amdgcn_mfma_f32_16x16x32_f16(A[6], BA0[6], v0, 0, 0, 0);
            v1 = __builtin_amdgcn_mfma_f32_16x16x32_f16(A[6], BA1[6], v1, 0, 0, 0);
            u0 = __builtin_amdgcn_mfma_f32_16x16x32_f16(A[3], BA0[3], u0, 0, 0, 0);
            u1 = __builtin_amdgcn_mfma_f32_16x16x32_f16(A[3], BA1[3], u1, 0, 0, 0);

            if (q == 0) {
                if (cv0) {
                    const float y   = (u0[0] + u0[1]) + (v0[0] + v0[1]);
                    const float pre = y + fmaf(x0, wx00, fmaf(x1, wx01, bA0));
                    const float e   = __expf(2.f * pre);
                    const float th  = 1.f - 2.f / (e + 1.f);
                    const unsigned short hi = f2h(th);
                    ring[sw][0][nA0] = hi;
                    ring[sw][1][nA0] = f2h(th - h2f(hi));
                }
                if (cv1) {
                    const float y   = (u1[0] + u1[1]) + (v1[0] + v1[1]);
                    const float pre = y + fmaf(x0, wx10, fmaf(x1, wx11, bA1));
                    const float e   = __expf(2.f * pre);
                    const float th  = 1.f - 2.f / (e + 1.f);
                    const unsigned short hi = f2h(th);
                    ring[sw][0][nA1] = hi;
                    ring[sw][1][nA1] = f2h(th - h2f(hi));
                }
            }
        } else {
            // single tile: 4/3 split chains (as R13)
            f4v u = {0.f, 0.f, 0.f, 0.f};
            f4v v = {0.f, 0.f, 0.f, 0.f};
            u = __builtin_amdgcn_mfma_f32_16x16x32_f16(A[0], BA0[0], u, 0, 0, 0);
            v = __builtin_amdgcn_mfma_f32_16x16x32_f16(A[4], BA0[4], v, 0, 0, 0);
            u = __builtin_amdgcn_mfma_f32_16x16x32_f16(A[1], BA0[1], u, 0, 0, 0);
            v = __builtin_amdgcn_mfma_f32_16x16x32_f16(A[5], BA0[5], v, 0, 0, 0);
            u = __builtin_amdgcn_mfma_f32_16x16x32_f16(A[2], BA0[2], u, 0, 0, 0);
            v = __builtin_amdgcn_mfma_f32_16x16x32_f16(A[6], BA0[6], v, 0, 0, 0);
            u = __builtin_amdgcn_mfma_f32_16x16x32_f16(A[3], BA0[3], u, 0, 0, 0);

            if (q == 0 && cv0) {
                const float y   = (u[0] + u[1]) + (v[0] + v[1]);
                const float pre = y + fmaf(x0, wx00, fmaf(x1, wx01, bA0));
                const float e   = __expf(2.f * pre);
                const float th  = 1.f - 2.f / (e + 1.f);
                const unsigned short hi = f2h(th);
                ring[sw][0][nA0] = hi;
                ring[sw][1][nA0] = f2h(th - h2f(hi));
            }
        }
        __syncthreads();
        if (++rp == RS) rp = 0;
    }

    // --- tail: T % RS == 0 -> last RS steps sit in slots 0..7 ---
    drain(w, T - RS + w);
}

extern "C" void kernel_launch(void* const* d_in, const int* in_sizes, int n_in,
                              void* d_out, int out_size, void* d_ws, size_t ws_size,
                              hipStream_t stream) {
    const float* x     = (const float*)d_in[0];
    const float* W_ih  = (const float*)d_in[1];
    const float* W_hh  = (const float*)d_in[2];
    const float* b_ih  = (const float*)d_in[3];
    const float* b_hh  = (const float*)d_in[4];
    const float* W_out = (const float*)d_in[5];
    const float* b_out = (const float*)d_in[6];
    float* out = (float*)d_out;

    rnn_fused<<<B, NTHR, 0, stream>>>(x, W_ih, W_hh, b_ih, b_hh, W_out, b_out, out);
}